// Round 6
// baseline (798.392 us; speedup 1.0000x reference)
//
#include <hip/hip_runtime.h>

#define NSEQ 4096
#define DDIM 1024
#define NROWS 8192
#define NROWS3 24576      // 3 branches * B * N
#define BAND 512
#define BM 128
#define BN 128
#define BKT 64
#define PT_W 768          // padded transposed-band window per 64-m chunk
#define PT_CH 64          // m-chunks per batch

typedef __attribute__((ext_vector_type(8))) __bf16 bf16x8;
typedef __attribute__((ext_vector_type(4))) float f32x4;

__device__ __forceinline__ unsigned short f2b(float f) {
  unsigned int u = __float_as_uint(f);
  unsigned int r = (u + 0x7FFFu + ((u >> 16) & 1u)) >> 16;
  return (unsigned short)r;
}
__device__ __forceinline__ float b2f(unsigned short b) {
  return __uint_as_float(((unsigned int)b) << 16);
}

// async global->LDS, 16B/lane; LDS dest wave-uniform (HW adds lane*16)
__device__ __forceinline__ void gload16(const unsigned short* g, unsigned short* l) {
  __builtin_amdgcn_global_load_lds(
      (const __attribute__((address_space(1))) void*)g,
      (__attribute__((address_space(3))) void*)l, 16, 0, 0);
}

// ---------------- block reductions (256 threads = 4 waves) ----------------
__device__ __forceinline__ float blk_sum(float v) {
  __shared__ float red_s[4];
  #pragma unroll
  for (int o = 32; o; o >>= 1) v += __shfl_xor(v, o);
  __syncthreads();
  if ((threadIdx.x & 63) == 0) red_s[threadIdx.x >> 6] = v;
  __syncthreads();
  return red_s[0] + red_s[1] + red_s[2] + red_s[3];
}
__device__ __forceinline__ float blk_max(float v) {
  __shared__ float red_m[4];
  #pragma unroll
  for (int o = 32; o; o >>= 1) v = fmaxf(v, __shfl_xor(v, o));
  __syncthreads();
  if ((threadIdx.x & 63) == 0) red_m[threadIdx.x >> 6] = v;
  __syncthreads();
  return fmaxf(fmaxf(red_m[0], red_m[1]), fmaxf(red_m[2], red_m[3]));
}

// ---------------- fused f32 -> bf16 converts ----------------
__global__ __launch_bounds__(256) void k_cvt_w(
    const float* __restrict__ w0, const float* __restrict__ w1,
    const float* __restrict__ w2, const float* __restrict__ w3,
    const float* __restrict__ w4, const float* __restrict__ w5,
    const float* __restrict__ w6, unsigned short* __restrict__ dst)
{
  int y = blockIdx.y;
  const float* src = (y == 0) ? w0 : (y == 1) ? w1 : (y == 2) ? w2 :
                     (y == 3) ? w3 : (y == 4) ? w4 : (y == 5) ? w5 : w6;
  int i = blockIdx.x * 256 + threadIdx.x;
  float4 f = ((const float4*)src)[i];
  ushort4 o = make_ushort4(f2b(f.x), f2b(f.y), f2b(f.z), f2b(f.w));
  ((ushort4*)(dst + (size_t)y * DDIM * DDIM))[i] = o;
}

__global__ __launch_bounds__(256) void k_cvt3(
    const float* __restrict__ x1, const float* __restrict__ x2,
    const float* __restrict__ x3, unsigned short* __restrict__ dst)
{
  int y = blockIdx.y;
  const float* src = (y == 0) ? x1 : (y == 1) ? x2 : x3;
  int i = blockIdx.x * 256 + threadIdx.x;
  float4 f = ((const float4*)src)[i];
  ushort4 o = make_ushort4(f2b(f.x), f2b(f.y), f2b(f.z), f2b(f.w));
  ((ushort4*)(dst + (size_t)y * NROWS * DDIM))[i] = o;
}

// ============ 256x256 GEMM, m201-style phase schedule (T3+T4+T5), K=1024 ====
// 8 waves (2M x 4N), per-wave 128x64 out; LDS 2 x 64KB double-buffer.
// Per K-tile: 4 phases, each = one C-quadrant (16 MFMA):
//   {12x ds_read_b128 -> s_barrier -> lgkmcnt(0)+sched_barrier -> setprio(1)
//    16 MFMA -> setprio(0) -> s_barrier}
// Stage of tile t+2 issues at the tile boundary (only race-free slot with
// 2 buffers); counted vmcnt(8) keeps it in flight across the next whole tile
// (T4 - never drains to 0 mid-loop). T2 chunk-swizzle via pre-swizzled global
// source (linear gload_lds dest), undone on ds_read.
// OMODE 0: bf16 out (+bias, opt relu); OMODE 1: QKV epilogue (K/Q*0.06/Vt).
template<int OMODE>
__global__ __launch_bounds__(512, 2) void k_gemm256(
    const unsigned short* __restrict__ A,
    const unsigned short* __restrict__ B,
    unsigned short* __restrict__ Cout,
    const float* __restrict__ bias, int relu, int nby,
    unsigned short* __restrict__ Kout,
    unsigned short* __restrict__ Qout,
    unsigned short* __restrict__ Vtout)
{
  __shared__ unsigned short lds[65536];   // 128 KiB
  const int tid = threadIdx.x;
  const int lane = tid & 63, wid = tid >> 6;     // 8 waves
  const int wm = wid >> 2, wn = wid & 3;         // 2 x 4
  const int lrow = lane & 15, kgrp = lane >> 4;
  const int srow = lane >> 3;                    // 0..7
  const int schunk = (lane & 7) ^ srow;          // pre-swizzled source chunk

  // bijective XCD swizzle (nwg divisible by 8)
  const int nwg = gridDim.x;
  const int q8 = nwg >> 3;
  const int flat = blockIdx.x;
  const int logical = (flat & 7) * q8 + (flat >> 3);
  const size_t m0 = (size_t)(logical / nby) * 256;
  const size_t n0 = (size_t)(logical % nby) * 256;

  f32x4 acc[8][4] = {};

  // one K-tile (A 256x64 + B 256x64): 8 gload16/thread
  #define STAGE256(buf, k0)                                                   \
    {                                                                         \
      unsigned short* dA = lds + (buf) * 32768 + wid * 2048;                  \
      unsigned short* dB = dA + 16384;                                        \
      _Pragma("unroll")                                                       \
      for (int l = 0; l < 4; ++l) {                                           \
        int row = wid * 32 + l * 8 + srow;                                    \
        gload16(A + (m0 + row) * 1024 + (k0) + schunk * 8, dA + l * 512);     \
        gload16(B + (n0 + row) * 1024 + (k0) + schunk * 8, dB + l * 512);     \
      }                                                                       \
    }

  STAGE256(0, 0)
  STAGE256(1, 64)
  asm volatile("s_waitcnt vmcnt(8)" ::: "memory");   // tile 0 landed
  __builtin_amdgcn_s_barrier();
  __builtin_amdgcn_sched_barrier(0);

  int cur = 0;
  #pragma unroll 1
  for (int t = 0; t < 16; ++t) {
    const unsigned short* As = lds + cur * 32768;
    const unsigned short* Bs = As + 16384;
    // 4 phases per K-tile: phase p = quadrant (qn = p>>1, qm = p&1)
    #pragma unroll
    for (int p = 0; p < 4; ++p) {
      const int qn = p >> 1, qm = p & 1;
      bf16x8 bfr[2][2], af[4][2];
      #pragma unroll
      for (int j = 0; j < 2; ++j)
        #pragma unroll
        for (int ks = 0; ks < 2; ++ks) {
          int rb = wn * 64 + qn * 32 + j * 16 + lrow;
          bfr[j][ks] = *(const bf16x8*)&Bs[rb * 64 + (((ks * 4 + kgrp) ^ (rb & 7)) << 3)];
        }
      #pragma unroll
      for (int i = 0; i < 4; ++i)
        #pragma unroll
        for (int ks = 0; ks < 2; ++ks) {
          int ra = wm * 128 + qm * 64 + i * 16 + lrow;
          af[i][ks] = *(const bf16x8*)&As[ra * 64 + (((ks * 4 + kgrp) ^ (ra & 7)) << 3)];
        }
      __builtin_amdgcn_s_barrier();                       // phase-lock waves
      asm volatile("s_waitcnt lgkmcnt(0)" ::: "memory");  // my ds_reads done
      __builtin_amdgcn_sched_barrier(0);                  // rule #18: pin MFMA after wait
      __builtin_amdgcn_s_setprio(1);
      #pragma unroll
      for (int i = 0; i < 4; ++i)
        #pragma unroll
        for (int j = 0; j < 2; ++j)
          #pragma unroll
          for (int ks = 0; ks < 2; ++ks)
            acc[qm * 4 + i][qn * 2 + j] = __builtin_amdgcn_mfma_f32_16x16x32_bf16(
                af[i][ks], bfr[j][ks], acc[qm * 4 + i][qn * 2 + j], 0, 0, 0);
      __builtin_amdgcn_s_setprio(0);
      __builtin_amdgcn_s_barrier();
      __builtin_amdgcn_sched_barrier(0);
    }
    if (t == 15) break;
    // tile boundary: buf[cur] fully consumed by everyone (post-MFMA barrier
    // of phase 3) -> safe to refill. Counted vmcnt: tile t+1 must have
    // landed; tile t+2's 8 loads stay in flight across the next tile.
    if (t < 14) {
      STAGE256(cur, (t + 2) * 64)
      asm volatile("s_waitcnt vmcnt(8)" ::: "memory");
    } else {
      asm volatile("s_waitcnt vmcnt(0)" ::: "memory");    // tail drain
    }
    __builtin_amdgcn_s_barrier();
    __builtin_amdgcn_sched_barrier(0);
    cur ^= 1;
  }
  #undef STAGE256

  // ---- epilogue ----
  if (OMODE == 1) {
    const int seg = (int)(n0 >> 10);                // block-uniform
    const float al = (seg == 1) ? 0.06f : 1.f;
    #pragma unroll
    for (int ai = 0; ai < 8; ++ai) {
      int rbase = (int)m0 + wm * 128 + (ai >> 2) * 64 + (ai & 3) * 16 + kgrp * 4;
      #pragma unroll
      for (int bj = 0; bj < 4; ++bj) {
        int col = (int)n0 + wn * 64 + (bj >> 1) * 32 + (bj & 1) * 16 + lrow;
        int d = col & 1023;
        if (seg == 2) {
          int z = rbase >> 12, nn = rbase & (NSEQ - 1);
          ushort4 o;
          o.x = f2b(acc[ai][bj][0]);
          o.y = f2b(acc[ai][bj][1]);
          o.z = f2b(acc[ai][bj][2]);
          o.w = f2b(acc[ai][bj][3]);
          *(ushort4*)&Vtout[((size_t)z * DDIM + d) * NSEQ + nn] = o;
        } else {
          unsigned short* dst = (seg == 1 ? Qout : Kout);
          #pragma unroll
          for (int r = 0; r < 4; ++r)
            dst[(size_t)(rbase + r) * DDIM + d] = f2b(acc[ai][bj][r] * al);
        }
      }
    }
  } else {
    #pragma unroll
    for (int ai = 0; ai < 8; ++ai) {
      int rbase = (int)m0 + wm * 128 + (ai >> 2) * 64 + (ai & 3) * 16 + kgrp * 4;
      #pragma unroll
      for (int bj = 0; bj < 4; ++bj) {
        int col = (int)n0 + wn * 64 + (bj >> 1) * 32 + (bj & 1) * 16 + lrow;
        float bv = bias ? bias[col] : 0.f;
        #pragma unroll
        for (int r = 0; r < 4; ++r) {
          float v = acc[ai][bj][r] + bv;
          if (relu) v = fmaxf(v, 0.f);
          Cout[(size_t)(rbase + r) * 1024 + col] = f2b(v);
        }
      }
    }
  }
}

// ---------------- banded QK^T: S_band[z][m][j], j = n-m+255 ----------------
__global__ __launch_bounds__(256) void k_qk_banded(
    const unsigned short* __restrict__ Q,
    const unsigned short* __restrict__ Kmat,
    float* __restrict__ Sb)
{
  const int m0 = blockIdx.x * BM;
  const int n0 = m0 - 256 + blockIdx.y * BM;
  const int z = blockIdx.z;
  if (n0 + BM <= 0 || n0 >= NSEQ) return;
  const unsigned short* Ab = Q + (size_t)z * NSEQ * DDIM;
  const unsigned short* Bb = Kmat + (size_t)z * NSEQ * DDIM;
  __shared__ unsigned short As[BM * BKT];
  __shared__ unsigned short Bs[BN * BKT];
  const int tid = threadIdx.x;
  const int lane = tid & 63, wave = tid >> 6;
  const int wm = wave >> 1, wn = wave & 1;
  const int lrow = lane & 15, kgrp = lane >> 4;
  const int srow = lane >> 3;
  const int sseg = (lane & 7) ^ srow;
  f32x4 acc[4][4] = {};

  for (int k0 = 0; k0 < DDIM; k0 += BKT) {
    #pragma unroll
    for (int i = 0; i < 4; ++i) {
      int chunk = wave * 4 + i;
      int row = chunk * 8 + srow;
      gload16(Ab + (size_t)(m0 + row) * DDIM + k0 + sseg * 8, As + chunk * 512);
      int nr = n0 + row;
      nr = nr < 0 ? 0 : (nr >= NSEQ ? NSEQ - 1 : nr);   // clamped; garbage masked by band
      gload16(Bb + (size_t)nr * DDIM + k0 + sseg * 8, Bs + chunk * 512);
    }
    __syncthreads();
    #pragma unroll
    for (int ks = 0; ks < 2; ++ks) {
      bf16x8 af[4], bfr[4];
      #pragma unroll
      for (int i = 0; i < 4; ++i)
        af[i] = *(const bf16x8*)&As[(wm * 64 + i * 16 + lrow) * BKT +
                                    (((ks * 4 + kgrp) ^ (lrow & 7)) << 3)];
      #pragma unroll
      for (int j = 0; j < 4; ++j)
        bfr[j] = *(const bf16x8*)&Bs[(wn * 64 + j * 16 + lrow) * BKT +
                                     (((ks * 4 + kgrp) ^ (lrow & 7)) << 3)];
      #pragma unroll
      for (int i = 0; i < 4; ++i)
        #pragma unroll
        for (int j = 0; j < 4; ++j)
          acc[i][j] = __builtin_amdgcn_mfma_f32_16x16x32_bf16(af[i], bfr[j], acc[i][j], 0, 0, 0);
    }
    __syncthreads();
  }

  float* Sz = Sb + (size_t)z * NSEQ * BAND;
  #pragma unroll
  for (int i = 0; i < 4; ++i) {
    #pragma unroll
    for (int j = 0; j < 4; ++j) {
      int n = n0 + wn * 64 + j * 16 + lrow;
      #pragma unroll
      for (int r = 0; r < 4; ++r) {
        int m = m0 + wm * 64 + i * 16 + kgrp * 4 + r;
        int dlt = n - m;
        if (n >= 0 && n < NSEQ && dlt >= -255 && dlt <= 255)
          Sz[(size_t)m * BAND + (dlt + 255)] = acc[i][j][r];
      }
    }
  }
}

// ---------------- banded softmax (one block per row) ----------------
__global__ __launch_bounds__(256) void k_softmax(
    const float* __restrict__ Sb, unsigned short* __restrict__ Pb)
{
  int row = blockIdx.x;           // z*N + m
  int m = row & (NSEQ - 1);
  int tid = threadIdx.x;
  int jlo = max(0, 255 - m);
  int jhi = min(510, NSEQ - 1 - m + 255);
  const float* S = Sb + (size_t)row * BAND;
  int j0 = tid, j1 = tid + 256;
  bool ok0 = (j0 >= jlo) && (j0 <= jhi);
  bool ok1 = (j1 >= jlo) && (j1 <= jhi);
  float v0 = ok0 ? S[j0] : -1e30f;
  float v1 = ok1 ? S[j1] : -1e30f;
  float mx = blk_max(fmaxf(v0, v1));
  float e0 = ok0 ? __expf(v0 - mx) : 0.f;
  float e1 = ok1 ? __expf(v1 - mx) : 0.f;
  float sum = blk_sum(e0 + e1);
  float inv = 1.f / sum;
  unsigned short* P = Pb + (size_t)row * BAND;
  P[j0] = f2b(e0 * inv);
  P[j1] = f2b(e1 * inv);
}

// ------- band transpose: Pt[z][c][n'][m'] = P[c*64+m'][n], n = c*64-320+n' -------
__global__ __launch_bounds__(256) void k_transpose(
    const unsigned short* __restrict__ Pb, unsigned short* __restrict__ Pt)
{
  const int c = blockIdx.x;        // 0..63
  const int s = blockIdx.y;        // 0..5
  const int z = blockIdx.z;        // 0..5
  const unsigned short* Pbb = Pb + (size_t)z * NSEQ * BAND;
  unsigned short* Ptb = Pt + ((size_t)z * PT_CH + c) * PT_W * 64;
  __shared__ unsigned short Ts[64][130];
  const int t = threadIdx.x;
  const int half = t >> 7;
  const int jl = t & 127;
  #pragma unroll
  for (int e = 0; e < 32; ++e) {
    int mp = e * 2 + half;
    int j = s * 128 + jl - mp - 65;
    unsigned short v = 0;
    if (j >= 0 && j < BAND) v = Pbb[(size_t)(c * 64 + mp) * BAND + j];
    Ts[mp][jl] = v;
  }
  __syncthreads();
  const int nl = t >> 1;
  const int mg = t & 1;
  unsigned short* orow = Ptb + (size_t)(s * 128 + nl) * 64;
  #pragma unroll
  for (int v4 = 0; v4 < 4; ++v4) {
    int lc = mg * 4 + v4;
    int sc = lc ^ (nl & 7);
    __align__(16) unsigned short tmp[8];
    #pragma unroll
    for (int i = 0; i < 8; ++i) tmp[i] = Ts[lc * 8 + i][nl];
    *(uint4*)(orow + sc * 8) = *(const uint4*)tmp;
  }
}

// ---------------- PV banded GEMM: Ya[(z*4096+n)][d] = sum_m Pt[n][m] * V[m][d] ----------------
__global__ __launch_bounds__(256) void k_pv(
    const unsigned short* __restrict__ Pt,   // [6][64 ch][768][64], chunk-swizzled
    const unsigned short* __restrict__ Vt,   // [6][DDIM][NSEQ]
    unsigned short* __restrict__ Y)          // [24576][DDIM]
{
  const int n0 = blockIdx.x * BM;
  const int d0 = blockIdx.y * BN;
  const int z = blockIdx.z;
  const int tid = threadIdx.x;
  const int lane = tid & 63, wave = tid >> 6;
  const int wm = wave >> 1, wn = wave & 1;
  const int lrow = lane & 15, kgrp = lane >> 4;
  const int srow = lane >> 3;
  const int sseg = (lane & 7) ^ srow;
  __shared__ unsigned short As[BM * BKT];
  __shared__ unsigned short Bs[BN * BKT];
  f32x4 acc[4][4] = {};
  const unsigned short* Ptb = Pt + (size_t)z * PT_CH * PT_W * 64;
  const unsigned short* Vtb = Vt + (size_t)z * DDIM * NSEQ;

  for (int kk = 0; kk < 10; ++kk) {
    int mb = n0 - 256 + kk * 64;
    if (mb < 0 || mb >= NSEQ) continue;      // block-uniform
    int c = mb >> 6;
    int np0 = 576 - kk * 64;
    const unsigned short* Abase = Ptb + ((size_t)c * PT_W + np0) * 64;
    #pragma unroll
    for (int i = 0; i < 4; ++i) {
      int chunk = wave * 4 + i;
      int row = chunk * 8 + srow;
      gload16(Abase + chunk * 512 + (size_t)lane * 8, As + chunk * 512);   // pre-swizzled
      gload16(Vtb + (size_t)(d0 + row) * NSEQ + mb + sseg * 8, Bs + chunk * 512);
    }
    __syncthreads();
    #pragma unroll
    for (int ks = 0; ks < 2; ++ks) {
      bf16x8 af[4], bfr[4];
      #pragma unroll
      for (int i = 0; i < 4; ++i)
        af[i] = *(const bf16x8*)&As[(wm * 64 + i * 16 + lrow) * BKT +
                                    (((ks * 4 + kgrp) ^ (lrow & 7)) << 3)];
      #pragma unroll
      for (int j = 0; j < 4; ++j)
        bfr[j] = *(const bf16x8*)&Bs[(wn * 64 + j * 16 + lrow) * BKT +
                                     (((ks * 4 + kgrp) ^ (lrow & 7)) << 3)];
      #pragma unroll
      for (int i = 0; i < 4; ++i)
        #pragma unroll
        for (int j = 0; j < 4; ++j)
          acc[i][j] = __builtin_amdgcn_mfma_f32_16x16x32_bf16(af[i], bfr[j], acc[i][j], 0, 0, 0);
    }
    __syncthreads();
  }

  unsigned short* Yb = Y + (size_t)z * NSEQ * DDIM;
  #pragma unroll
  for (int i = 0; i < 4; ++i) {
    int nb = n0 + wm * 64 + i * 16 + kgrp * 4;
    #pragma unroll
    for (int j = 0; j < 4; ++j) {
      int d = d0 + wn * 64 + j * 16 + lrow;
      #pragma unroll
      for (int r = 0; r < 4; ++r)
        Yb[(size_t)(nb + r) * DDIM + d] = f2b(acc[i][j][r]);
    }
  }
}

// ------- fused triple-LN: yB[r] = bf16( sum_br LN(aB[br*8192+r] + x_br[r]) ) -------
__global__ __launch_bounds__(256) void k_ln3(
    const unsigned short* __restrict__ aB,
    const float* __restrict__ x1, const float* __restrict__ x2,
    const float* __restrict__ x3,
    const float* __restrict__ g, const float* __restrict__ bb,
    unsigned short* __restrict__ yB)
{
  int row = blockIdx.x;                 // 0..8191
  int tid = threadIdx.x;
  const float* xs[3] = {x1, x2, x3};
  float o[4] = {0.f, 0.f, 0.f, 0.f};
  float4 g4 = ((const float4*)g)[tid];
  float4 b4 = ((const float4*)bb)[tid];
  #pragma unroll
  for (int br = 0; br < 3; ++br) {
    const unsigned short* a = aB + (size_t)(br * NROWS + row) * DDIM;
    const float* x = xs[br] + (size_t)row * DDIM;
    ushort4 a4 = ((const ushort4*)a)[tid];
    float4 x4 = ((const float4*)x)[tid];
    float v[4];
    v[0] = b2f(a4.x) + x4.x;
    v[1] = b2f(a4.y) + x4.y;
    v[2] = b2f(a4.z) + x4.z;
    v[3] = b2f(a4.w) + x4.w;
    float mu = blk_sum(v[0] + v[1] + v[2] + v[3]) * (1.f / DDIM);
    float qq = 0.f;
    #pragma unroll
    for (int i = 0; i < 4; ++i) { float d = v[i] - mu; qq += d * d; }
    float var = blk_sum(qq) * (1.f / (DDIM - 1));     // ddof=1
    float inv = 1.f / (sqrtf(var) + 1e-6f);           // eps on std
    o[0] += g4.x * (v[0] - mu) * inv + b4.x;
    o[1] += g4.y * (v[1] - mu) * inv + b4.y;
    o[2] += g4.z * (v[2] - mu) * inv + b4.z;
    o[3] += g4.w * (v[3] - mu) * inv + b4.w;
  }
  ushort4 w = make_ushort4(f2b(o[0]), f2b(o[1]), f2b(o[2]), f2b(o[3]));
  ((ushort4*)(yB + (size_t)row * DDIM))[tid] = w;
}

// ---------------- final: LN(relu'd h3) then dot with kd_w ----------------
__global__ __launch_bounds__(256) void k_ln_dot(
    const unsigned short* __restrict__ H,
    const float* __restrict__ g, const float* __restrict__ bb,
    const float* __restrict__ kw, const float* __restrict__ kb,
    float* __restrict__ out)
{
  int row = blockIdx.x;
  int tid = threadIdx.x;
  const unsigned short* h = H + (size_t)row * DDIM;
  ushort4 h4 = ((const ushort4*)h)[tid];
  float v[4] = {b2f(h4.x), b2f(h4.y), b2f(h4.z), b2f(h4.w)};
  float mu = blk_sum(v[0] + v[1] + v[2] + v[3]) * (1.f / DDIM);
  float qq = 0.f;
  #pragma unroll
  for (int i = 0; i < 4; ++i) { float d = v[i] - mu; qq += d * d; }
  float var = blk_sum(qq) * (1.f / (DDIM - 1));
  float inv = 1.f / (sqrtf(var) + 1e-6f);
  float4 g4 = ((const float4*)g)[tid];
  float4 b4 = ((const float4*)bb)[tid];
  float4 k4 = ((const float4*)kw)[tid];
  float p = (g4.x * (v[0] - mu) * inv + b4.x) * k4.x
          + (g4.y * (v[1] - mu) * inv + b4.y) * k4.y
          + (g4.z * (v[2] - mu) * inv + b4.z) * k4.z
          + (g4.w * (v[3] - mu) * inv + b4.w) * k4.w;
  float tot = blk_sum(p);
  if (tid == 0) out[row] = tot + kb[0];
}

extern "C" void kernel_launch(void* const* d_in, const int* in_sizes, int n_in,
                              void* d_out, int out_size, void* d_ws, size_t ws_size,
                              hipStream_t stream)
{
  const float* x1 = (const float*)d_in[0];
  const float* x2 = (const float*)d_in[1];
  const float* x3 = (const float*)d_in[2];
  const float* Wk = (const float*)d_in[3];
  const float* Wq = (const float*)d_in[4];
  const float* Wv = (const float*)d_in[5];
  const float* Wo = (const float*)d_in[6];
  const float* ka_w = (const float*)d_in[7];
  const float* ka_b = (const float*)d_in[8];
  const float* kb_w = (const float*)d_in[9];
  const float* kb_b = (const float*)d_in[10];
  const float* kc_w = (const float*)d_in[11];
  const float* kc_b = (const float*)d_in[12];
  const float* kd_w = (const float*)d_in[13];
  const float* kd_b = (const float*)d_in[14];
  const float* g1 = (const float*)d_in[15];
  const float* b1 = (const float*)d_in[16];
  const float* g2 = (const float*)d_in[17];
  const float* b2 = (const float*)d_in[18];

  // ---- 256 MiB arena, phase-aliased (peak 206 MB) ----
  const size_t MB = 1024ull * 1024ull;
  char* base = (char*)d_ws;
  unsigned short* WkB = (unsigned short*)(base + 0 * MB);   // [Wk;Wq;Wv;Wo;ka;kb;kc]
  unsigned short* WoB = (unsigned short*)(base + 6 * MB);
  unsigned short* kaB = (unsigned short*)(base + 8 * MB);
  unsigned short* kbB = (unsigned short*)(base + 10 * MB);
  unsigned short* kcB = (unsigned short*)(base + 12 * MB);
  // [14,62): xB -> Sb -> aB
  unsigned short* xB = (unsigned short*)(base + 14 * MB);   // [24576][1024] bf16
  float* Sb = (float*)(base + 14 * MB);                     // [6][4096][512] f32
  unsigned short* aB = (unsigned short*)(base + 14 * MB);   // [24576][1024] bf16
  // [62,110): Kb -> Pb -> Ya
  unsigned short* Kb = (unsigned short*)(base + 62 * MB);   // [6][4096][1024] bf16
  unsigned short* Pb = (unsigned short*)(base + 62 * MB);   // [6][4096][512] bf16
  unsigned short* Ya = (unsigned short*)(base + 62 * MB);   // [24576][1024] bf16
  // [110,158): Qb -> Pt -> {yB,h1,h2}
  unsigned short* Qb = (unsigned short*)(base + 110 * MB);  // [6][4096][1024] bf16
  unsigned short* PtB = (unsigned short*)(base + 110 * MB); // [6][64][768][64] bf16 (36MB)
  unsigned short* yB = (unsigned short*)(base + 110 * MB);  // 16MB
  unsigned short* h1 = (unsigned short*)(base + 126 * MB);  // 16MB
  unsigned short* h2 = (unsigned short*)(base + 142 * MB);  // 16MB
  // [158,206): Vt -> h3
  unsigned short* VtB = (unsigned short*)(base + 158 * MB); // [6][1024][4096] bf16
  unsigned short* h3 = (unsigned short*)(base + 158 * MB);  // 16MB
  (void)ws_size; (void)in_sizes; (void)n_in; (void)out_size;

  dim3 blk(256), blk5(512);
  k_cvt_w<<<dim3(1024, 7), blk, 0, stream>>>(Wk, Wq, Wv, Wo, ka_w, kb_w, kc_w, WkB);
  k_cvt3<<<dim3(8192, 3), blk, 0, stream>>>(x1, x2, x3, xB);

  // fused QKV over all branches: [24576 x 3072] (1152 blocks)
  k_gemm256<1><<<dim3(96 * 12), blk5, 0, stream>>>(xB, WkB, nullptr, nullptr, 0, 12,
                                                   Kb, Qb, VtB);
  // attention middle, batched z = 3 branches * 2 batch
  k_qk_banded<<<dim3(NSEQ / BM, 5, 6), blk, 0, stream>>>(Qb, Kb, Sb);
  k_softmax<<<NROWS3, blk, 0, stream>>>(Sb, Pb);
  k_transpose<<<dim3(PT_CH, PT_W / 128, 6), blk, 0, stream>>>(Pb, PtB);
  k_pv<<<dim3(NSEQ / BM, DDIM / BN, 6), blk, 0, stream>>>(PtB, VtB, Ya);
  // fused Wo over [24576 x 1024] (384 blocks)
  k_gemm256<0><<<dim3(96 * 4), blk5, 0, stream>>>(Ya, WoB, aB, nullptr, 0, 4,
                                                  nullptr, nullptr, nullptr);
  // fused triple-LN -> bf16 MLP input
  k_ln3<<<NROWS, blk, 0, stream>>>(aB, x1, x2, x3, g1, b1, yB);
  // MLP (each 128 blocks)
  k_gemm256<0><<<dim3(32 * 4), blk5, 0, stream>>>(yB, kaB, h1, ka_b, 0, 4,
                                                  nullptr, nullptr, nullptr);
  k_gemm256<0><<<dim3(32 * 4), blk5, 0, stream>>>(h1, kbB, h2, kb_b, 0, 4,
                                                  nullptr, nullptr, nullptr);
  k_gemm256<0><<<dim3(32 * 4), blk5, 0, stream>>>(h2, kcB, h3, kc_b, 1, 4,
                                                  nullptr, nullptr, nullptr);
  k_ln_dot<<<NROWS, blk, 0, stream>>>(h3, g2, b2, kd_w, kd_b, (float*)d_out);
}

// Round 7
// 708.837 us; speedup vs baseline: 1.1263x; 1.1263x over previous
//
#include <hip/hip_runtime.h>

#define NSEQ 4096
#define DDIM 1024
#define NROWS 8192
#define NROWS3 24576      // 3 branches * B * N
#define BAND 512
#define BM 128
#define BN 128
#define BKT 64
#define PT_W 768          // padded transposed-band window per 64-m chunk
#define PT_CH 64          // m-chunks per batch

typedef __attribute__((ext_vector_type(8))) __bf16 bf16x8;
typedef __attribute__((ext_vector_type(4))) float f32x4;

__device__ __forceinline__ unsigned short f2b(float f) {
  unsigned int u = __float_as_uint(f);
  unsigned int r = (u + 0x7FFFu + ((u >> 16) & 1u)) >> 16;
  return (unsigned short)r;
}
__device__ __forceinline__ float b2f(unsigned short b) {
  return __uint_as_float(((unsigned int)b) << 16);
}

// async global->LDS, 16B/lane; LDS dest wave-uniform (HW adds lane*16)
__device__ __forceinline__ void gload16(const unsigned short* g, unsigned short* l) {
  __builtin_amdgcn_global_load_lds(
      (const __attribute__((address_space(1))) void*)g,
      (__attribute__((address_space(3))) void*)l, 16, 0, 0);
}

// ---------------- block reductions (256 threads = 4 waves) ----------------
__device__ __forceinline__ float blk_sum(float v) {
  __shared__ float red_s[4];
  #pragma unroll
  for (int o = 32; o; o >>= 1) v += __shfl_xor(v, o);
  __syncthreads();
  if ((threadIdx.x & 63) == 0) red_s[threadIdx.x >> 6] = v;
  __syncthreads();
  return red_s[0] + red_s[1] + red_s[2] + red_s[3];
}
__device__ __forceinline__ float blk_max(float v) {
  __shared__ float red_m[4];
  #pragma unroll
  for (int o = 32; o; o >>= 1) v = fmaxf(v, __shfl_xor(v, o));
  __syncthreads();
  if ((threadIdx.x & 63) == 0) red_m[threadIdx.x >> 6] = v;
  __syncthreads();
  return fmaxf(fmaxf(red_m[0], red_m[1]), fmaxf(red_m[2], red_m[3]));
}

// ---------------- fused f32 -> bf16 converts ----------------
__global__ __launch_bounds__(256) void k_cvt_w(
    const float* __restrict__ w0, const float* __restrict__ w1,
    const float* __restrict__ w2, const float* __restrict__ w3,
    const float* __restrict__ w4, const float* __restrict__ w5,
    const float* __restrict__ w6, unsigned short* __restrict__ dst)
{
  int y = blockIdx.y;
  const float* src = (y == 0) ? w0 : (y == 1) ? w1 : (y == 2) ? w2 :
                     (y == 3) ? w3 : (y == 4) ? w4 : (y == 5) ? w5 : w6;
  int i = blockIdx.x * 256 + threadIdx.x;
  float4 f = ((const float4*)src)[i];
  ushort4 o = make_ushort4(f2b(f.x), f2b(f.y), f2b(f.z), f2b(f.w));
  ((ushort4*)(dst + (size_t)y * DDIM * DDIM))[i] = o;
}

__global__ __launch_bounds__(256) void k_cvt3(
    const float* __restrict__ x1, const float* __restrict__ x2,
    const float* __restrict__ x3, unsigned short* __restrict__ dst)
{
  int y = blockIdx.y;
  const float* src = (y == 0) ? x1 : (y == 1) ? x2 : x3;
  int i = blockIdx.x * 256 + threadIdx.x;
  float4 f = ((const float4*)src)[i];
  ushort4 o = make_ushort4(f2b(f.x), f2b(f.y), f2b(f.z), f2b(f.w));
  ((ushort4*)(dst + (size_t)y * NROWS * DDIM))[i] = o;
}

// ============ 256x256 GEMM, 2-phase/tile + counted vmcnt (R4-proven) ========
// 8 waves (2M x 4N), per-wave 128x64 out; LDS 2 x 64KB double-buffer (1 blk/CU).
// Counted vmcnt(8): tile t+2's loads stay in flight across tile t+1 (T4).
// T2 chunk-swizzle via pre-swizzled global source, undone on ds_read.
// OMODE 0: bf16 out (+bias, opt relu); OMODE 1: QKV epilogue (K/Q*0.06/Vt).
template<int OMODE>
__global__ __launch_bounds__(512, 2) void k_gemm256(
    const unsigned short* __restrict__ A,
    const unsigned short* __restrict__ B,
    unsigned short* __restrict__ Cout,
    const float* __restrict__ bias, int relu, int nby,
    unsigned short* __restrict__ Kout,
    unsigned short* __restrict__ Qout,
    unsigned short* __restrict__ Vtout)
{
  __shared__ unsigned short lds[65536];   // 128 KiB
  const int tid = threadIdx.x;
  const int lane = tid & 63, wid = tid >> 6;     // 8 waves
  const int wm = wid >> 2, wn = wid & 3;         // 2 x 4
  const int lrow = lane & 15, kgrp = lane >> 4;
  const int srow = lane >> 3;                    // 0..7
  const int schunk = (lane & 7) ^ srow;          // pre-swizzled source chunk

  // bijective XCD swizzle (nwg divisible by 8)
  const int nwg = gridDim.x;
  const int q8 = nwg >> 3;
  const int flat = blockIdx.x;
  const int logical = (flat & 7) * q8 + (flat >> 3);
  const size_t m0 = (size_t)(logical / nby) * 256;
  const size_t n0 = (size_t)(logical % nby) * 256;

  f32x4 acc[8][4] = {};

  // one K-tile (A 256x64 + B 256x64): 8 gload16/thread
  #define STAGE256(buf, k0)                                                   \
    {                                                                         \
      unsigned short* dA = lds + (buf) * 32768 + wid * 2048;                  \
      unsigned short* dB = dA + 16384;                                        \
      _Pragma("unroll")                                                       \
      for (int l = 0; l < 4; ++l) {                                           \
        int row = wid * 32 + l * 8 + srow;                                    \
        gload16(A + (m0 + row) * 1024 + (k0) + schunk * 8, dA + l * 512);     \
        gload16(B + (n0 + row) * 1024 + (k0) + schunk * 8, dB + l * 512);     \
      }                                                                       \
    }

  STAGE256(0, 0)
  STAGE256(1, 64)
  asm volatile("s_waitcnt vmcnt(8)" ::: "memory");   // tile 0 landed
  __builtin_amdgcn_s_barrier();
  __builtin_amdgcn_sched_barrier(0);

  int cur = 0;
  #pragma unroll 1
  for (int t = 0; t < 16; ++t) {
    const unsigned short* As = lds + cur * 32768;
    const unsigned short* Bs = As + 16384;
    // 4 quadrant groups: qn outer (reuse B frags), qm inner
    #pragma unroll
    for (int qn = 0; qn < 2; ++qn) {
      bf16x8 bfr[2][2];
      #pragma unroll
      for (int j = 0; j < 2; ++j)
        #pragma unroll
        for (int ks = 0; ks < 2; ++ks) {
          int rb = wn * 64 + qn * 32 + j * 16 + lrow;
          bfr[j][ks] = *(const bf16x8*)&Bs[rb * 64 + (((ks * 4 + kgrp) ^ (rb & 7)) << 3)];
        }
      #pragma unroll
      for (int qm = 0; qm < 2; ++qm) {
        bf16x8 af[4][2];
        #pragma unroll
        for (int i = 0; i < 4; ++i)
          #pragma unroll
          for (int ks = 0; ks < 2; ++ks) {
            int ra = wm * 128 + qm * 64 + i * 16 + lrow;
            af[i][ks] = *(const bf16x8*)&As[ra * 64 + (((ks * 4 + kgrp) ^ (ra & 7)) << 3)];
          }
        __builtin_amdgcn_s_setprio(1);
        #pragma unroll
        for (int i = 0; i < 4; ++i)
          #pragma unroll
          for (int j = 0; j < 2; ++j)
            #pragma unroll
            for (int ks = 0; ks < 2; ++ks)
              acc[qm * 4 + i][qn * 2 + j] = __builtin_amdgcn_mfma_f32_16x16x32_bf16(
                  af[i][ks], bfr[j][ks], acc[qm * 4 + i][qn * 2 + j], 0, 0, 0);
        __builtin_amdgcn_s_setprio(0);
      }
    }
    if (t == 15) break;
    __builtin_amdgcn_s_barrier();          // everyone done reading buf[cur]
    __builtin_amdgcn_sched_barrier(0);
    if (t < 14) {
      STAGE256(cur, (t + 2) * 64)          // refill the buffer just freed
      asm volatile("s_waitcnt vmcnt(8)" ::: "memory");  // tile t+1 landed
    } else {
      asm volatile("s_waitcnt vmcnt(0)" ::: "memory");  // drain last tile
    }
    __builtin_amdgcn_s_barrier();          // all waves' staging visible
    __builtin_amdgcn_sched_barrier(0);
    cur ^= 1;
  }
  #undef STAGE256

  // ---- epilogue ----
  if (OMODE == 1) {
    const int seg = (int)(n0 >> 10);                // block-uniform
    const float al = (seg == 1) ? 0.06f : 1.f;
    #pragma unroll
    for (int ai = 0; ai < 8; ++ai) {
      int rbase = (int)m0 + wm * 128 + (ai >> 2) * 64 + (ai & 3) * 16 + kgrp * 4;
      #pragma unroll
      for (int bj = 0; bj < 4; ++bj) {
        int col = (int)n0 + wn * 64 + (bj >> 1) * 32 + (bj & 1) * 16 + lrow;
        int d = col & 1023;
        if (seg == 2) {
          int z = rbase >> 12, nn = rbase & (NSEQ - 1);
          ushort4 o;
          o.x = f2b(acc[ai][bj][0]);
          o.y = f2b(acc[ai][bj][1]);
          o.z = f2b(acc[ai][bj][2]);
          o.w = f2b(acc[ai][bj][3]);
          *(ushort4*)&Vtout[((size_t)z * DDIM + d) * NSEQ + nn] = o;
        } else {
          unsigned short* dst = (seg == 1 ? Qout : Kout);
          #pragma unroll
          for (int r = 0; r < 4; ++r)
            dst[(size_t)(rbase + r) * DDIM + d] = f2b(acc[ai][bj][r] * al);
        }
      }
    }
  } else {
    #pragma unroll
    for (int ai = 0; ai < 8; ++ai) {
      int rbase = (int)m0 + wm * 128 + (ai >> 2) * 64 + (ai & 3) * 16 + kgrp * 4;
      #pragma unroll
      for (int bj = 0; bj < 4; ++bj) {
        int col = (int)n0 + wn * 64 + (bj >> 1) * 32 + (bj & 1) * 16 + lrow;
        float bv = bias ? bias[col] : 0.f;
        #pragma unroll
        for (int r = 0; r < 4; ++r) {
          float v = acc[ai][bj][r] + bv;
          if (relu) v = fmaxf(v, 0.f);
          Cout[(size_t)(rbase + r) * 1024 + col] = f2b(v);
        }
      }
    }
  }
}

// ---------- 128x128 dense GEMM (4-wave, 5 blk/CU) for MLP: full-GPU grid ----------
__global__ __launch_bounds__(256) void k_gemm128(
    const unsigned short* __restrict__ A,
    const unsigned short* __restrict__ B,
    unsigned short* __restrict__ Cout,
    const float* __restrict__ bias, int relu)
{
  __shared__ unsigned short As[BM * BKT];
  __shared__ unsigned short Bs[BN * BKT];
  const int tid = threadIdx.x;
  const int lane = tid & 63, wave = tid >> 6;
  const int wm = wave >> 1, wn = wave & 1;
  const int lrow = lane & 15, kgrp = lane >> 4;
  const int srow = lane >> 3;
  const int sseg = (lane & 7) ^ srow;
  const size_t m0 = (size_t)blockIdx.x * BM;
  const size_t n0 = (size_t)blockIdx.y * BN;
  f32x4 acc[4][4] = {};

  for (int k0 = 0; k0 < DDIM; k0 += BKT) {
    #pragma unroll
    for (int i = 0; i < 4; ++i) {
      int chunk = wave * 4 + i;
      int row = chunk * 8 + srow;
      gload16(A + (m0 + row) * (size_t)DDIM + k0 + sseg * 8, As + chunk * 512);
      gload16(B + (n0 + row) * (size_t)DDIM + k0 + sseg * 8, Bs + chunk * 512);
    }
    __syncthreads();
    #pragma unroll
    for (int ks = 0; ks < 2; ++ks) {
      bf16x8 af[4], bfr[4];
      #pragma unroll
      for (int i = 0; i < 4; ++i)
        af[i] = *(const bf16x8*)&As[(wm * 64 + i * 16 + lrow) * BKT +
                                    (((ks * 4 + kgrp) ^ (lrow & 7)) << 3)];
      #pragma unroll
      for (int j = 0; j < 4; ++j)
        bfr[j] = *(const bf16x8*)&Bs[(wn * 64 + j * 16 + lrow) * BKT +
                                     (((ks * 4 + kgrp) ^ (lrow & 7)) << 3)];
      #pragma unroll
      for (int i = 0; i < 4; ++i)
        #pragma unroll
        for (int j = 0; j < 4; ++j)
          acc[i][j] = __builtin_amdgcn_mfma_f32_16x16x32_bf16(af[i], bfr[j], acc[i][j], 0, 0, 0);
    }
    __syncthreads();
  }

  #pragma unroll
  for (int i = 0; i < 4; ++i) {
    int rbase = (int)m0 + wm * 64 + i * 16 + kgrp * 4;
    #pragma unroll
    for (int j = 0; j < 4; ++j) {
      int col = (int)n0 + wn * 64 + j * 16 + lrow;
      float bv = bias ? bias[col] : 0.f;
      #pragma unroll
      for (int r = 0; r < 4; ++r) {
        float v = acc[i][j][r] + bv;
        if (relu) v = fmaxf(v, 0.f);
        Cout[(size_t)(rbase + r) * DDIM + col] = f2b(v);
      }
    }
  }
}

// ---------------- banded QK^T: S_band[z][m][j], j = n-m+255 ----------------
__global__ __launch_bounds__(256) void k_qk_banded(
    const unsigned short* __restrict__ Q,
    const unsigned short* __restrict__ Kmat,
    float* __restrict__ Sb)
{
  const int m0 = blockIdx.x * BM;
  const int n0 = m0 - 256 + blockIdx.y * BM;
  const int z = blockIdx.z;
  if (n0 + BM <= 0 || n0 >= NSEQ) return;
  const unsigned short* Ab = Q + (size_t)z * NSEQ * DDIM;
  const unsigned short* Bb = Kmat + (size_t)z * NSEQ * DDIM;
  __shared__ unsigned short As[BM * BKT];
  __shared__ unsigned short Bs[BN * BKT];
  const int tid = threadIdx.x;
  const int lane = tid & 63, wave = tid >> 6;
  const int wm = wave >> 1, wn = wave & 1;
  const int lrow = lane & 15, kgrp = lane >> 4;
  const int srow = lane >> 3;
  const int sseg = (lane & 7) ^ srow;
  f32x4 acc[4][4] = {};

  for (int k0 = 0; k0 < DDIM; k0 += BKT) {
    #pragma unroll
    for (int i = 0; i < 4; ++i) {
      int chunk = wave * 4 + i;
      int row = chunk * 8 + srow;
      gload16(Ab + (size_t)(m0 + row) * DDIM + k0 + sseg * 8, As + chunk * 512);
      int nr = n0 + row;
      nr = nr < 0 ? 0 : (nr >= NSEQ ? NSEQ - 1 : nr);   // clamped; garbage masked by band
      gload16(Bb + (size_t)nr * DDIM + k0 + sseg * 8, Bs + chunk * 512);
    }
    __syncthreads();
    #pragma unroll
    for (int ks = 0; ks < 2; ++ks) {
      bf16x8 af[4], bfr[4];
      #pragma unroll
      for (int i = 0; i < 4; ++i)
        af[i] = *(const bf16x8*)&As[(wm * 64 + i * 16 + lrow) * BKT +
                                    (((ks * 4 + kgrp) ^ (lrow & 7)) << 3)];
      #pragma unroll
      for (int j = 0; j < 4; ++j)
        bfr[j] = *(const bf16x8*)&Bs[(wn * 64 + j * 16 + lrow) * BKT +
                                     (((ks * 4 + kgrp) ^ (lrow & 7)) << 3)];
      #pragma unroll
      for (int i = 0; i < 4; ++i)
        #pragma unroll
        for (int j = 0; j < 4; ++j)
          acc[i][j] = __builtin_amdgcn_mfma_f32_16x16x32_bf16(af[i], bfr[j], acc[i][j], 0, 0, 0);
    }
    __syncthreads();
  }

  float* Sz = Sb + (size_t)z * NSEQ * BAND;
  #pragma unroll
  for (int i = 0; i < 4; ++i) {
    #pragma unroll
    for (int j = 0; j < 4; ++j) {
      int n = n0 + wn * 64 + j * 16 + lrow;
      #pragma unroll
      for (int r = 0; r < 4; ++r) {
        int m = m0 + wm * 64 + i * 16 + kgrp * 4 + r;
        int dlt = n - m;
        if (n >= 0 && n < NSEQ && dlt >= -255 && dlt <= 255)
          Sz[(size_t)m * BAND + (dlt + 255)] = acc[i][j][r];
      }
    }
  }
}

// ---------------- banded softmax (one block per row) ----------------
__global__ __launch_bounds__(256) void k_softmax(
    const float* __restrict__ Sb, unsigned short* __restrict__ Pb)
{
  int row = blockIdx.x;           // z*N + m
  int m = row & (NSEQ - 1);
  int tid = threadIdx.x;
  int jlo = max(0, 255 - m);
  int jhi = min(510, NSEQ - 1 - m + 255);
  const float* S = Sb + (size_t)row * BAND;
  int j0 = tid, j1 = tid + 256;
  bool ok0 = (j0 >= jlo) && (j0 <= jhi);
  bool ok1 = (j1 >= jlo) && (j1 <= jhi);
  float v0 = ok0 ? S[j0] : -1e30f;
  float v1 = ok1 ? S[j1] : -1e30f;
  float mx = blk_max(fmaxf(v0, v1));
  float e0 = ok0 ? __expf(v0 - mx) : 0.f;
  float e1 = ok1 ? __expf(v1 - mx) : 0.f;
  float sum = blk_sum(e0 + e1);
  float inv = 1.f / sum;
  unsigned short* P = Pb + (size_t)row * BAND;
  P[j0] = f2b(e0 * inv);
  P[j1] = f2b(e1 * inv);
}

// ------- band transpose: Pt[z][c][n'][m'] = P[c*64+m'][n], n = c*64-320+n' -------
__global__ __launch_bounds__(256) void k_transpose(
    const unsigned short* __restrict__ Pb, unsigned short* __restrict__ Pt)
{
  const int c = blockIdx.x;        // 0..63
  const int s = blockIdx.y;        // 0..5
  const int z = blockIdx.z;        // 0..5
  const unsigned short* Pbb = Pb + (size_t)z * NSEQ * BAND;
  unsigned short* Ptb = Pt + ((size_t)z * PT_CH + c) * PT_W * 64;
  __shared__ unsigned short Ts[64][130];
  const int t = threadIdx.x;
  const int half = t >> 7;
  const int jl = t & 127;
  #pragma unroll
  for (int e = 0; e < 32; ++e) {
    int mp = e * 2 + half;
    int j = s * 128 + jl - mp - 65;
    unsigned short v = 0;
    if (j >= 0 && j < BAND) v = Pbb[(size_t)(c * 64 + mp) * BAND + j];
    Ts[mp][jl] = v;
  }
  __syncthreads();
  const int nl = t >> 1;
  const int mg = t & 1;
  unsigned short* orow = Ptb + (size_t)(s * 128 + nl) * 64;
  #pragma unroll
  for (int v4 = 0; v4 < 4; ++v4) {
    int lc = mg * 4 + v4;
    int sc = lc ^ (nl & 7);
    __align__(16) unsigned short tmp[8];
    #pragma unroll
    for (int i = 0; i < 8; ++i) tmp[i] = Ts[lc * 8 + i][nl];
    *(uint4*)(orow + sc * 8) = *(const uint4*)tmp;
  }
}

// ---------------- PV banded GEMM: Ya[(z*4096+n)][d] = sum_m Pt[n][m] * V[m][d] ----------------
__global__ __launch_bounds__(256) void k_pv(
    const unsigned short* __restrict__ Pt,   // [6][64 ch][768][64], chunk-swizzled
    const unsigned short* __restrict__ Vt,   // [6][DDIM][NSEQ]
    unsigned short* __restrict__ Y)          // [24576][DDIM]
{
  const int n0 = blockIdx.x * BM;
  const int d0 = blockIdx.y * BN;
  const int z = blockIdx.z;
  const int tid = threadIdx.x;
  const int lane = tid & 63, wave = tid >> 6;
  const int wm = wave >> 1, wn = wave & 1;
  const int lrow = lane & 15, kgrp = lane >> 4;
  const int srow = lane >> 3;
  const int sseg = (lane & 7) ^ srow;
  __shared__ unsigned short As[BM * BKT];
  __shared__ unsigned short Bs[BN * BKT];
  f32x4 acc[4][4] = {};
  const unsigned short* Ptb = Pt + (size_t)z * PT_CH * PT_W * 64;
  const unsigned short* Vtb = Vt + (size_t)z * DDIM * NSEQ;

  for (int kk = 0; kk < 10; ++kk) {
    int mb = n0 - 256 + kk * 64;
    if (mb < 0 || mb >= NSEQ) continue;      // block-uniform
    int c = mb >> 6;
    int np0 = 576 - kk * 64;
    const unsigned short* Abase = Ptb + ((size_t)c * PT_W + np0) * 64;
    #pragma unroll
    for (int i = 0; i < 4; ++i) {
      int chunk = wave * 4 + i;
      int row = chunk * 8 + srow;
      gload16(Abase + chunk * 512 + (size_t)lane * 8, As + chunk * 512);   // pre-swizzled
      gload16(Vtb + (size_t)(d0 + row) * NSEQ + mb + sseg * 8, Bs + chunk * 512);
    }
    __syncthreads();
    #pragma unroll
    for (int ks = 0; ks < 2; ++ks) {
      bf16x8 af[4], bfr[4];
      #pragma unroll
      for (int i = 0; i < 4; ++i)
        af[i] = *(const bf16x8*)&As[(wm * 64 + i * 16 + lrow) * BKT +
                                    (((ks * 4 + kgrp) ^ (lrow & 7)) << 3)];
      #pragma unroll
      for (int j = 0; j < 4; ++j)
        bfr[j] = *(const bf16x8*)&Bs[(wn * 64 + j * 16 + lrow) * BKT +
                                     (((ks * 4 + kgrp) ^ (lrow & 7)) << 3)];
      #pragma unroll
      for (int i = 0; i < 4; ++i)
        #pragma unroll
        for (int j = 0; j < 4; ++j)
          acc[i][j] = __builtin_amdgcn_mfma_f32_16x16x32_bf16(af[i], bfr[j], acc[i][j], 0, 0, 0);
    }
    __syncthreads();
  }

  unsigned short* Yb = Y + (size_t)z * NSEQ * DDIM;
  #pragma unroll
  for (int i = 0; i < 4; ++i) {
    int nb = n0 + wm * 64 + i * 16 + kgrp * 4;
    #pragma unroll
    for (int j = 0; j < 4; ++j) {
      int d = d0 + wn * 64 + j * 16 + lrow;
      #pragma unroll
      for (int r = 0; r < 4; ++r)
        Yb[(size_t)(nb + r) * DDIM + d] = f2b(acc[i][j][r]);
    }
  }
}

// ------- fused triple-LN: yB[r] = bf16( sum_br LN(aB[br*8192+r] + x_br[r]) ) -------
__global__ __launch_bounds__(256) void k_ln3(
    const unsigned short* __restrict__ aB,
    const float* __restrict__ x1, const float* __restrict__ x2,
    const float* __restrict__ x3,
    const float* __restrict__ g, const float* __restrict__ bb,
    unsigned short* __restrict__ yB)
{
  int row = blockIdx.x;                 // 0..8191
  int tid = threadIdx.x;
  const float* xs[3] = {x1, x2, x3};
  float o[4] = {0.f, 0.f, 0.f, 0.f};
  float4 g4 = ((const float4*)g)[tid];
  float4 b4 = ((const float4*)bb)[tid];
  #pragma unroll
  for (int br = 0; br < 3; ++br) {
    const unsigned short* a = aB + (size_t)(br * NROWS + row) * DDIM;
    const float* x = xs[br] + (size_t)row * DDIM;
    ushort4 a4 = ((const ushort4*)a)[tid];
    float4 x4 = ((const float4*)x)[tid];
    float v[4];
    v[0] = b2f(a4.x) + x4.x;
    v[1] = b2f(a4.y) + x4.y;
    v[2] = b2f(a4.z) + x4.z;
    v[3] = b2f(a4.w) + x4.w;
    float mu = blk_sum(v[0] + v[1] + v[2] + v[3]) * (1.f / DDIM);
    float qq = 0.f;
    #pragma unroll
    for (int i = 0; i < 4; ++i) { float d = v[i] - mu; qq += d * d; }
    float var = blk_sum(qq) * (1.f / (DDIM - 1));     // ddof=1
    float inv = 1.f / (sqrtf(var) + 1e-6f);           // eps on std
    o[0] += g4.x * (v[0] - mu) * inv + b4.x;
    o[1] += g4.y * (v[1] - mu) * inv + b4.y;
    o[2] += g4.z * (v[2] - mu) * inv + b4.z;
    o[3] += g4.w * (v[3] - mu) * inv + b4.w;
  }
  ushort4 w = make_ushort4(f2b(o[0]), f2b(o[1]), f2b(o[2]), f2b(o[3]));
  ((ushort4*)(yB + (size_t)row * DDIM))[tid] = w;
}

// ---------------- final: LN(relu'd h3) then dot with kd_w ----------------
__global__ __launch_bounds__(256) void k_ln_dot(
    const unsigned short* __restrict__ H,
    const float* __restrict__ g, const float* __restrict__ bb,
    const float* __restrict__ kw, const float* __restrict__ kb,
    float* __restrict__ out)
{
  int row = blockIdx.x;
  int tid = threadIdx.x;
  const unsigned short* h = H + (size_t)row * DDIM;
  ushort4 h4 = ((const ushort4*)h)[tid];
  float v[4] = {b2f(h4.x), b2f(h4.y), b2f(h4.z), b2f(h4.w)};
  float mu = blk_sum(v[0] + v[1] + v[2] + v[3]) * (1.f / DDIM);
  float qq = 0.f;
  #pragma unroll
  for (int i = 0; i < 4; ++i) { float d = v[i] - mu; qq += d * d; }
  float var = blk_sum(qq) * (1.f / (DDIM - 1));
  float inv = 1.f / (sqrtf(var) + 1e-6f);
  float4 g4 = ((const float4*)g)[tid];
  float4 b4 = ((const float4*)bb)[tid];
  float4 k4 = ((const float4*)kw)[tid];
  float p = (g4.x * (v[0] - mu) * inv + b4.x) * k4.x
          + (g4.y * (v[1] - mu) * inv + b4.y) * k4.y
          + (g4.z * (v[2] - mu) * inv + b4.z) * k4.z
          + (g4.w * (v[3] - mu) * inv + b4.w) * k4.w;
  float tot = blk_sum(p);
  if (tid == 0) out[row] = tot + kb[0];
}

extern "C" void kernel_launch(void* const* d_in, const int* in_sizes, int n_in,
                              void* d_out, int out_size, void* d_ws, size_t ws_size,
                              hipStream_t stream)
{
  const float* x1 = (const float*)d_in[0];
  const float* x2 = (const float*)d_in[1];
  const float* x3 = (const float*)d_in[2];
  const float* Wk = (const float*)d_in[3];
  const float* Wq = (const float*)d_in[4];
  const float* Wv = (const float*)d_in[5];
  const float* Wo = (const float*)d_in[6];
  const float* ka_w = (const float*)d_in[7];
  const float* ka_b = (const float*)d_in[8];
  const float* kb_w = (const float*)d_in[9];
  const float* kb_b = (const float*)d_in[10];
  const float* kc_w = (const float*)d_in[11];
  const float* kc_b = (const float*)d_in[12];
  const float* kd_w = (const float*)d_in[13];
  const float* kd_b = (const float*)d_in[14];
  const float* g1 = (const float*)d_in[15];
  const float* b1 = (const float*)d_in[16];
  const float* g2 = (const float*)d_in[17];
  const float* b2 = (const float*)d_in[18];

  // ---- 256 MiB arena, phase-aliased (peak 206 MB) ----
  const size_t MB = 1024ull * 1024ull;
  char* base = (char*)d_ws;
  unsigned short* WkB = (unsigned short*)(base + 0 * MB);   // [Wk;Wq;Wv;Wo;ka;kb;kc]
  unsigned short* WoB = (unsigned short*)(base + 6 * MB);
  unsigned short* kaB = (unsigned short*)(base + 8 * MB);
  unsigned short* kbB = (unsigned short*)(base + 10 * MB);
  unsigned short* kcB = (unsigned short*)(base + 12 * MB);
  // [14,62): xB -> Sb -> aB
  unsigned short* xB = (unsigned short*)(base + 14 * MB);   // [24576][1024] bf16
  float* Sb = (float*)(base + 14 * MB);                     // [6][4096][512] f32
  unsigned short* aB = (unsigned short*)(base + 14 * MB);   // [24576][1024] bf16
  // [62,110): Kb -> Pb -> Ya
  unsigned short* Kb = (unsigned short*)(base + 62 * MB);   // [6][4096][1024] bf16
  unsigned short* Pb = (unsigned short*)(base + 62 * MB);   // [6][4096][512] bf16
  unsigned short* Ya = (unsigned short*)(base + 62 * MB);   // [24576][1024] bf16
  // [110,158): Qb -> Pt -> {yB,h1,h2}
  unsigned short* Qb = (unsigned short*)(base + 110 * MB);  // [6][4096][1024] bf16
  unsigned short* PtB = (unsigned short*)(base + 110 * MB); // [6][64][768][64] bf16 (36MB)
  unsigned short* yB = (unsigned short*)(base + 110 * MB);  // 16MB
  unsigned short* h1 = (unsigned short*)(base + 126 * MB);  // 16MB
  unsigned short* h2 = (unsigned short*)(base + 142 * MB);  // 16MB
  // [158,206): Vt -> h3
  unsigned short* VtB = (unsigned short*)(base + 158 * MB); // [6][1024][4096] bf16
  unsigned short* h3 = (unsigned short*)(base + 158 * MB);  // 16MB
  (void)ws_size; (void)in_sizes; (void)n_in; (void)out_size;

  dim3 blk(256), blk5(512);
  k_cvt_w<<<dim3(1024, 7), blk, 0, stream>>>(Wk, Wq, Wv, Wo, ka_w, kb_w, kc_w, WkB);
  k_cvt3<<<dim3(8192, 3), blk, 0, stream>>>(x1, x2, x3, xB);

  // fused QKV over all branches: [24576 x 3072] (1152 blocks, 4.5 waves @1/CU)
  k_gemm256<1><<<dim3(96 * 12), blk5, 0, stream>>>(xB, WkB, nullptr, nullptr, 0, 12,
                                                   Kb, Qb, VtB);
  // attention middle, batched z = 3 branches * 2 batch
  k_qk_banded<<<dim3(NSEQ / BM, 5, 6), blk, 0, stream>>>(Qb, Kb, Sb);
  k_softmax<<<NROWS3, blk, 0, stream>>>(Sb, Pb);
  k_transpose<<<dim3(PT_CH, PT_W / 128, 6), blk, 0, stream>>>(Pb, PtB);
  k_pv<<<dim3(NSEQ / BM, DDIM / BN, 6), blk, 0, stream>>>(PtB, VtB, Ya);
  // fused Wo over [24576 x 1024] (384 blocks)
  k_gemm256<0><<<dim3(96 * 4), blk5, 0, stream>>>(Ya, WoB, aB, nullptr, 0, 4,
                                                  nullptr, nullptr, nullptr);
  // fused triple-LN -> bf16 MLP input
  k_ln3<<<NROWS, blk, 0, stream>>>(aB, x1, x2, x3, g1, b1, yB);
  // MLP on 128^2 grid (512 blocks, 5 blk/CU -> full GPU in one wave)
  dim3 gm(NROWS / BM, DDIM / BN);
  k_gemm128<<<gm, blk, 0, stream>>>(yB, kaB, h1, ka_b, 0);
  k_gemm128<<<gm, blk, 0, stream>>>(h1, kbB, h2, kb_b, 0);
  k_gemm128<<<gm, blk, 0, stream>>>(h2, kcB, h3, kc_b, 1);
  k_ln_dot<<<NROWS, blk, 0, stream>>>(h3, g2, b2, kd_w, kd_b, (float*)d_out);
}